// Round 4
// baseline (2095.464 us; speedup 1.0000x reference)
//
#include <hip/hip_runtime.h>

#define TSTEPS 2048
#define NBATCH 512
#define H1 64
#define H2 16

__device__ __forceinline__ float fsig(float x) {
    return __builtin_amdgcn_rcpf(1.0f + __builtin_amdgcn_exp2f(-1.4426950408889634f * x));
}
__device__ __forceinline__ float ftanh(float x) {
    // tanh(x) = 1 - 2/(exp2(2x*log2e)+1); saturates correctly at +-inf
    return 1.0f - 2.0f * __builtin_amdgcn_rcpf(1.0f + __builtin_amdgcn_exp2f(2.8853900817779268f * x));
}

// DPP cross-lane add (VALU pipe, not LDS)
#define DPP_QUAD_XOR1   0xB1   // quad_perm [1,0,3,2]
#define DPP_QUAD_XOR2   0x4E   // quad_perm [2,3,0,1]
#define DPP_HALF_MIRROR 0x141  // mirror within 8-lane group
template<int CTRL>
__device__ __forceinline__ float dpp_add(float v) {
    int m = __builtin_amdgcn_mov_dpp(__float_as_int(v), CTRL, 0xF, 0xF, true);
    return v + __int_as_float(m);
}

// Wave-specialized: waves 0-3 = layer 1 (256 thr), waves 4-5 = layer 2 (128 thr).
// Peak per-thread register demand ~105 (one weight set + temps), under any
// plausible RA budget — round-3 evidence: combined demand ~145 spilled at 88.
__global__ void __launch_bounds__(384, 2)
lstm2_fused(const float* __restrict__ x,      // [512, 2048, 1]
            const float* __restrict__ w_ih1,  // [256, 1]
            const float* __restrict__ w_hh1,  // [256, 64]
            const float* __restrict__ b_ih1,  // [256]
            const float* __restrict__ b_hh1,  // [256]
            const float* __restrict__ w_ih2,  // [64, 64]
            const float* __restrict__ w_hh2,  // [64, 16]
            const float* __restrict__ b_ih2,  // [64]
            const float* __restrict__ b_hh2,  // [64]
            float* __restrict__ out)          // [512, 2048, 16]
{
    const int b   = blockIdx.x;
    const int tid = threadIdx.x;

    __shared__ float x_lds[TSTEPS];
    __shared__ float h1buf[2][H1];
    __shared__ float h2buf[2][H2];

    // ---- stage x[b,:] (8 KB), zero state buffers ----
    {
        const float4* xs = reinterpret_cast<const float4*>(x + (size_t)b * TSTEPS);
        float4* xd = reinterpret_cast<float4*>(x_lds);
        xd[tid] = xs[tid];
        if (tid < TSTEPS / 4 - 384) xd[384 + tid] = xs[384 + tid];
    }
    if (tid < 2 * H1) ((float*)h1buf)[tid] = 0.0f;
    else if (tid < 2 * H1 + 2 * H2) ((float*)h2buf)[tid - 2 * H1] = 0.0f;

    // ================= per-wave-group weight residency =================
    // Layer 1 (tid<256): channel j = tid>>2, k-quarter q = tid&3.
    // Thread owns all 4 gate rows {j,64+j,128+j,192+j}, k-slice [q*16, q*16+16).
    const int j = tid >> 2;
    const int q = tid & 3;
    float w1[4][16], wx1[4], bs1[4];
    // Layer 2 (tid>=256): tt = tid-256, channel m = tt>>3, octant oc = tt&7.
    const int tt = tid - 256;
    const int m  = tt >> 3;
    const int oc = tt & 7;
    float w2[4][8], wh2[4][2], bs2[4];

    if (tid < 256) {
        #pragma unroll
        for (int g = 0; g < 4; ++g) {
            const int r = g * H1 + j;
            const float4* w4 = reinterpret_cast<const float4*>(w_hh1 + r * H1 + q * 16);
            #pragma unroll
            for (int kk = 0; kk < 4; ++kk) {
                float4 v = w4[kk];
                w1[g][4*kk+0] = v.x; w1[g][4*kk+1] = v.y;
                w1[g][4*kk+2] = v.z; w1[g][4*kk+3] = v.w;
            }
            wx1[g] = w_ih1[r];
            bs1[g] = b_ih1[r] + b_hh1[r];
        }
        // opaque defs: forbid load-sinking/remat of the weights into the loop
        #pragma unroll
        for (int g = 0; g < 4; ++g) {
            #pragma unroll
            for (int k = 0; k < 16; ++k) asm volatile("" : "+v"(w1[g][k]));
            asm volatile("" : "+v"(wx1[g]), "+v"(bs1[g]));
        }
    } else {
        #pragma unroll
        for (int g = 0; g < 4; ++g) {
            const int r2 = g * H2 + m;
            const float4* w4 = reinterpret_cast<const float4*>(w_ih2 + r2 * H1 + oc * 8);
            float4 v0 = w4[0], v1 = w4[1];
            w2[g][0]=v0.x; w2[g][1]=v0.y; w2[g][2]=v0.z; w2[g][3]=v0.w;
            w2[g][4]=v1.x; w2[g][5]=v1.y; w2[g][6]=v1.z; w2[g][7]=v1.w;
            float2 vh = *reinterpret_cast<const float2*>(w_hh2 + r2 * H2 + oc * 2);
            wh2[g][0] = vh.x; wh2[g][1] = vh.y;
            bs2[g] = b_ih2[r2] + b_hh2[r2];
        }
        #pragma unroll
        for (int g = 0; g < 4; ++g) {
            #pragma unroll
            for (int k = 0; k < 8; ++k) asm volatile("" : "+v"(w2[g][k]));
            asm volatile("" : "+v"(wh2[g][0]), "+v"(wh2[g][1]), "+v"(bs2[g]));
        }
    }

    float c1 = 0.0f;   // layer-1 cell, replicated across the 4 q-lanes of channel j
    float c2 = 0.0f;   // layer-2 cell, replicated across the 8 oc-lanes of channel m
    __syncthreads();

    float* outb = out + (size_t)b * TSTEPS * H2;

    // Layer 2 computes timestep t-1 while layer-1 waves compute timestep t.
    // ONE barrier per step; h1/h2 double-buffered by parity.
    for (int t = 0; t <= TSTEPS; ++t) {
        const int ri = t & 1;                  // h1buf[ri]=h1(t-1), h2buf[ri]=h2(t-2)
        const float* h1o = h1buf[ri];

        if (tid < 256) {
            // ===== Layer 1, timestep t (waves 0-3) =====
            if (t < TSTEPS) {
                const float4* h4 = reinterpret_cast<const float4*>(h1o + q * 16);
                float4 v0 = h4[0], v1 = h4[1], v2 = h4[2], v3 = h4[3];
                const float x_t = x_lds[t];
                float pre[4];
                #pragma unroll
                for (int g = 0; g < 4; ++g) {
                    float sa = w1[g][0] *v0.x + w1[g][1] *v0.y + w1[g][2] *v0.z + w1[g][3] *v0.w;
                    sa      += w1[g][4] *v1.x + w1[g][5] *v1.y + w1[g][6] *v1.z + w1[g][7] *v1.w;
                    float sb = w1[g][8] *v2.x + w1[g][9] *v2.y + w1[g][10]*v2.z + w1[g][11]*v2.w;
                    sb      += w1[g][12]*v3.x + w1[g][13]*v3.y + w1[g][14]*v3.z + w1[g][15]*v3.w;
                    float s = sa + sb;
                    s = dpp_add<DPP_QUAD_XOR1>(s);      // all-reduce over 4 q-lanes
                    s = dpp_add<DPP_QUAD_XOR2>(s);
                    pre[g] = s + (x_t * wx1[g] + bs1[g]);
                }
                float gi = fsig(pre[0]), gf = fsig(pre[1]), gg = ftanh(pre[2]), go = fsig(pre[3]);
                c1 = gf * c1 + gi * gg;
                float h1n = go * ftanh(c1);
                if (q == 0) h1buf[ri ^ 1][j] = h1n;
            }
        } else {
            // ===== Layer 2, timestep t-1 (waves 4-5) =====
            if (t >= 1) {
                const float4* h4 = reinterpret_cast<const float4*>(h1o + oc * 8);
                float4 a0 = h4[0], a1 = h4[1];
                float h2a = h2buf[ri][oc * 2], h2b = h2buf[ri][oc * 2 + 1];
                float p[4];
                #pragma unroll
                for (int g = 0; g < 4; ++g) {
                    float s = w2[g][0]*a0.x + w2[g][1]*a0.y + w2[g][2]*a0.z + w2[g][3]*a0.w;
                    s      += w2[g][4]*a1.x + w2[g][5]*a1.y + w2[g][6]*a1.z + w2[g][7]*a1.w;
                    s      += wh2[g][0]*h2a + wh2[g][1]*h2b;
                    s = dpp_add<DPP_QUAD_XOR1>(s);      // all-reduce over 8 oc-lanes
                    s = dpp_add<DPP_QUAD_XOR2>(s);
                    s = dpp_add<DPP_HALF_MIRROR>(s);
                    p[g] = s + bs2[g];
                }
                float gi = fsig(p[0]), gf = fsig(p[1]), gg = ftanh(p[2]), go = fsig(p[3]);
                c2 = gf * c2 + gi * gg;
                float h2n = go * ftanh(c2);
                if (oc == 0) {
                    h2buf[ri ^ 1][m] = h2n;
                    outb[(size_t)(t - 1) * H2 + m] = h2n;
                }
            }
        }

        __syncthreads();   // publish h1(t) / h2(t-1) for iteration t+1
    }
}

extern "C" void kernel_launch(void* const* d_in, const int* in_sizes, int n_in,
                              void* d_out, int out_size, void* d_ws, size_t ws_size,
                              hipStream_t stream) {
    const float* x     = (const float*)d_in[0];
    const float* w_ih1 = (const float*)d_in[1];
    const float* w_hh1 = (const float*)d_in[2];
    const float* b_ih1 = (const float*)d_in[3];
    const float* b_hh1 = (const float*)d_in[4];
    const float* w_ih2 = (const float*)d_in[5];
    const float* w_hh2 = (const float*)d_in[6];
    const float* b_ih2 = (const float*)d_in[7];
    const float* b_hh2 = (const float*)d_in[8];
    float* out = (float*)d_out;

    lstm2_fused<<<NBATCH, 384, 0, stream>>>(x, w_ih1, w_hh1, b_ih1, b_hh1,
                                            w_ih2, w_hh2, b_ih2, b_hh2, out);
}